// Round 2
// baseline (22998.943 us; speedup 1.0000x reference)
//
#include <hip/hip_runtime.h>
#include <cstddef>
#include <math.h>

// Problem constants
#define T_TOK   32768   // total tokens = 1024 rows * 32
#define D_MODEL 1024
#define ROWS    1024    // b*NY sequences
#define HEADS   16
#define DH      64
#define DFF     4096
#define NQKV    3072
#define LLAYERS 2

#define RCHUNK  8192    // qkv row chunk (tokens)  -> 8192*3072 floats in B
#define FCHUNK  512     // MLP DFF col chunk       -> 32768*512 floats in B

// ---------------- fp32 tiled GEMM: C = A@W [+ bias] [+res] [gelu] --------
// BM=128, BN=64, BK=16, 256 threads, each thread 8x4 outputs.
// A: M x K (row stride K). W: K x N slice with row stride ldw.
// C/res: M x N (row stride N). Requires M%128==0, N%64==0, K%16==0.
#define BM 128
#define BN 64
#define BK 16

template<int EPI>  // 0: bias | 1: bias+res | 2: bias+gelu | 3: res only
__global__ __launch_bounds__(256) void gemm_f32(
    const float* __restrict__ A, const float* __restrict__ W,
    const float* __restrict__ bias, const float* __restrict__ res,
    float* __restrict__ C, int M, int N, int K, int ldw)
{
  __shared__ float As[BK][BM + 4];
  __shared__ float Ws[BK][BN + 4];
  const int tid = threadIdx.x;
  const int bm = blockIdx.x * BM;
  const int bn = blockIdx.y * BN;
  const int tx = tid & 15;   // col group 0..15 (4 cols each)
  const int ty = tid >> 4;   // row group 0..15 (8 rows each)
  float acc[8][4] = {};

  for (int k0 = 0; k0 < K; k0 += BK) {
    #pragma unroll
    for (int u = 0; u < 2; ++u) {
      int f  = u * 256 + tid;
      int r  = f >> 2;        // 0..127
      int c4 = f & 3;         // 0..3
      float4 v = *reinterpret_cast<const float4*>(&A[(size_t)(bm + r) * K + (k0 + c4 * 4)]);
      As[c4*4+0][r] = v.x; As[c4*4+1][r] = v.y; As[c4*4+2][r] = v.z; As[c4*4+3][r] = v.w;
    }
    {
      int r  = tid >> 4;      // 0..15
      int c4 = tid & 15;      // 0..15
      float4 v = *reinterpret_cast<const float4*>(&W[(size_t)(k0 + r) * ldw + (bn + c4 * 4)]);
      *reinterpret_cast<float4*>(&Ws[r][c4*4]) = v;
    }
    __syncthreads();
    #pragma unroll
    for (int kk = 0; kk < BK; ++kk) {
      float4 a0 = *reinterpret_cast<const float4*>(&As[kk][ty*8]);
      float4 a1 = *reinterpret_cast<const float4*>(&As[kk][ty*8+4]);
      float4 w0 = *reinterpret_cast<const float4*>(&Ws[kk][tx*4]);
      float av[8] = {a0.x,a0.y,a0.z,a0.w,a1.x,a1.y,a1.z,a1.w};
      float wv[4] = {w0.x,w0.y,w0.z,w0.w};
      #pragma unroll
      for (int i = 0; i < 8; ++i)
        #pragma unroll
        for (int j = 0; j < 4; ++j)
          acc[i][j] = fmaf(av[i], wv[j], acc[i][j]);
    }
    __syncthreads();
  }

  const int col = bn + tx*4;
  float4 b4 = make_float4(0.f, 0.f, 0.f, 0.f);
  if (EPI != 3) b4 = *reinterpret_cast<const float4*>(&bias[col]);
  #pragma unroll
  for (int i = 0; i < 8; ++i) {
    int row = bm + ty*8 + i;
    float4 v;
    v.x = acc[i][0] + b4.x; v.y = acc[i][1] + b4.y;
    v.z = acc[i][2] + b4.z; v.w = acc[i][3] + b4.w;
    if (EPI == 1 || EPI == 3) {
      float4 r4 = *reinterpret_cast<const float4*>(&res[(size_t)row * N + col]);
      v.x += r4.x; v.y += r4.y; v.z += r4.z; v.w += r4.w;
    }
    if (EPI == 2) {
      const float kA = 0.7978845608028654f, kB = 0.044715f;
      float t;
      t = v.x; v.x = 0.5f*t*(1.0f + tanhf(kA*(t + kB*t*t*t)));
      t = v.y; v.y = 0.5f*t*(1.0f + tanhf(kA*(t + kB*t*t*t)));
      t = v.z; v.z = 0.5f*t*(1.0f + tanhf(kA*(t + kB*t*t*t)));
      t = v.w; v.w = 0.5f*t*(1.0f + tanhf(kA*(t + kB*t*t*t)));
    }
    *reinterpret_cast<float4*>(&C[(size_t)row * N + col]) = v;
  }
}

// ---------------- LayerNorm: one wave per token ---------------------------
__global__ __launch_bounds__(256) void ln_kernel(
    const float* __restrict__ in, float* __restrict__ out,
    const float* __restrict__ w, const float* __restrict__ b)
{
  const int wv   = threadIdx.x >> 6;
  const int lane = threadIdx.x & 63;
  const size_t token = (size_t)blockIdx.x * 4 + wv;
  const float* row = in + token * D_MODEL;
  float4 v[4];
  float sum = 0.f;
  #pragma unroll
  for (int u = 0; u < 4; ++u) {
    v[u] = *reinterpret_cast<const float4*>(&row[lane*4 + u*256]);
    sum += (v[u].x + v[u].y) + (v[u].z + v[u].w);
  }
  #pragma unroll
  for (int off = 32; off > 0; off >>= 1) sum += __shfl_xor(sum, off, 64);
  const float mean = sum * (1.0f/1024.0f);
  float vs = 0.f;
  #pragma unroll
  for (int u = 0; u < 4; ++u) {
    float dx = v[u].x-mean, dy = v[u].y-mean, dz = v[u].z-mean, dw = v[u].w-mean;
    vs += dx*dx + dy*dy + dz*dz + dw*dw;
  }
  #pragma unroll
  for (int off = 32; off > 0; off >>= 1) vs += __shfl_xor(vs, off, 64);
  const float rstd = 1.0f / sqrtf(vs * (1.0f/1024.0f) + 1e-5f);
  float* orow = out + token * D_MODEL;
  #pragma unroll
  for (int u = 0; u < 4; ++u) {
    int col = lane*4 + u*256;
    float4 w4 = *reinterpret_cast<const float4*>(&w[col]);
    float4 b4 = *reinterpret_cast<const float4*>(&b[col]);
    float4 o;
    o.x = (v[u].x-mean)*rstd*w4.x + b4.x;
    o.y = (v[u].y-mean)*rstd*w4.y + b4.y;
    o.z = (v[u].z-mean)*rstd*w4.z + b4.z;
    o.w = (v[u].w-mean)*rstd*w4.w + b4.w;
    *reinterpret_cast<float4*>(&orow[col]) = o;
  }
}

// ---------------- Attention: one block per (seq, head), row-chunked QKV ----
// QKV holds RCHUNK tokens x 3072 (chunk-local rows). seq0 = first seq of chunk.
__global__ __launch_bounds__(256) void attn_kernel(
    const float* __restrict__ QKV, const float* __restrict__ mf,
    float* __restrict__ O, int seq0)
{
  const int bseq = blockIdx.x >> 4;        // chunk-local sequence
  const int head = blockIdx.x & 15;
  const int seq  = seq0 + bseq;            // global sequence
  __shared__ float Q[32][68];
  __shared__ float K[32][68];
  __shared__ float V[32][68];
  __shared__ float S[32][33];
  const int tid = threadIdx.x;

  #pragma unroll
  for (int u = 0; u < 2; ++u) {
    int f  = u * 256 + tid;
    int r  = f >> 4;        // 0..31
    int c4 = f & 15;        // 0..15
    size_t base = (size_t)(bseq*32 + r) * NQKV + head*DH + c4*4;
    *reinterpret_cast<float4*>(&Q[r][c4*4]) = *reinterpret_cast<const float4*>(&QKV[base]);
    *reinterpret_cast<float4*>(&K[r][c4*4]) = *reinterpret_cast<const float4*>(&QKV[base + 1024]);
    *reinterpret_cast<float4*>(&V[r][c4*4]) = *reinterpret_cast<const float4*>(&QKV[base + 2048]);
  }
  __syncthreads();

  {
    const int q   = tid >> 3;
    const int kk0 = (tid & 7) * 4;
    float s0=0.f, s1=0.f, s2=0.f, s3=0.f;
    #pragma unroll
    for (int d = 0; d < 64; d += 4) {
      float4 qv = *reinterpret_cast<const float4*>(&Q[q][d]);
      float4 k0 = *reinterpret_cast<const float4*>(&K[kk0+0][d]);
      float4 k1 = *reinterpret_cast<const float4*>(&K[kk0+1][d]);
      float4 k2 = *reinterpret_cast<const float4*>(&K[kk0+2][d]);
      float4 k3 = *reinterpret_cast<const float4*>(&K[kk0+3][d]);
      s0 += qv.x*k0.x + qv.y*k0.y + qv.z*k0.z + qv.w*k0.w;
      s1 += qv.x*k1.x + qv.y*k1.y + qv.z*k1.z + qv.w*k1.w;
      s2 += qv.x*k2.x + qv.y*k2.y + qv.z*k2.z + qv.w*k2.w;
      s3 += qv.x*k3.x + qv.y*k3.y + qv.z*k3.z + qv.w*k3.w;
    }
    float m0 = mf[seq*32 + kk0+0] > 0.f ? 0.f : -1e9f;
    float m1 = mf[seq*32 + kk0+1] > 0.f ? 0.f : -1e9f;
    float m2 = mf[seq*32 + kk0+2] > 0.f ? 0.f : -1e9f;
    float m3 = mf[seq*32 + kk0+3] > 0.f ? 0.f : -1e9f;
    S[q][kk0+0] = s0*0.125f + m0;
    S[q][kk0+1] = s1*0.125f + m1;
    S[q][kk0+2] = s2*0.125f + m2;
    S[q][kk0+3] = s3*0.125f + m3;
  }
  __syncthreads();

  if (tid < 32) {
    float m = S[tid][0];
    #pragma unroll
    for (int k = 1; k < 32; ++k) m = fmaxf(m, S[tid][k]);
    float sum = 0.f;
    #pragma unroll
    for (int k = 0; k < 32; ++k) { float e = expf(S[tid][k] - m); S[tid][k] = e; sum += e; }
    #pragma unroll
    for (int k = 0; k < 32; ++k) S[tid][k] = S[tid][k] / sum;
  }
  __syncthreads();

  {
    const int q  = tid >> 3;
    const int d0 = (tid & 7) * 8;
    float o[8] = {};
    #pragma unroll
    for (int kk = 0; kk < 32; ++kk) {
      float a = S[q][kk];
      float4 v0 = *reinterpret_cast<const float4*>(&V[kk][d0]);
      float4 v1 = *reinterpret_cast<const float4*>(&V[kk][d0+4]);
      o[0] += a*v0.x; o[1] += a*v0.y; o[2] += a*v0.z; o[3] += a*v0.w;
      o[4] += a*v1.x; o[5] += a*v1.y; o[6] += a*v1.z; o[7] += a*v1.w;
    }
    float* orow = O + (size_t)(seq*32 + q) * D_MODEL + head*DH + d0;
    *reinterpret_cast<float4*>(&orow[0]) = make_float4(o[0],o[1],o[2],o[3]);
    *reinterpret_cast<float4*>(&orow[4]) = make_float4(o[4],o[5],o[6],o[7]);
  }
}

// ---------------- Router logits + argmax: one wave per token --------------
__global__ __launch_bounds__(256) void router_kernel(
    const float* __restrict__ X, const float* __restrict__ Wf,
    const float* __restrict__ bf, int* __restrict__ chosen)
{
  const int wv   = threadIdx.x >> 6;
  const int lane = threadIdx.x & 63;
  const size_t token = (size_t)blockIdx.x * 4 + wv;
  const float* row = X + token * D_MODEL;
  float l0 = 0.f, l1 = 0.f, l2 = 0.f;
  #pragma unroll
  for (int u = 0; u < 4; ++u) {
    int d0 = lane*4 + u*256;
    float4 v = *reinterpret_cast<const float4*>(&row[d0]);
    const float* w = &Wf[(size_t)d0 * 3];
    l0 += v.x*w[0] + v.y*w[3] + v.z*w[6] + v.w*w[9];
    l1 += v.x*w[1] + v.y*w[4] + v.z*w[7] + v.w*w[10];
    l2 += v.x*w[2] + v.y*w[5] + v.z*w[8] + v.w*w[11];
  }
  #pragma unroll
  for (int off = 32; off > 0; off >>= 1) {
    l0 += __shfl_xor(l0, off, 64);
    l1 += __shfl_xor(l1, off, 64);
    l2 += __shfl_xor(l2, off, 64);
  }
  if (lane == 0) {
    l0 += bf[0]; l1 += bf[1]; l2 += bf[2];
    int c = 0; float best = l0;
    if (l1 > best) { best = l1; c = 1; }
    if (l2 > best) { best = l2; c = 2; }
    chosen[token] = c;
  }
}

// ---------------- masked copy: Xm = xf * mask -----------------------------
__global__ __launch_bounds__(256) void maskmul_kernel(
    const float* __restrict__ x, const float* __restrict__ mf, float* __restrict__ Xm)
{
  size_t i = (size_t)blockIdx.x * 256 + threadIdx.x;   // float4 index
  float m = mf[i >> 8];
  float4 v = reinterpret_cast<const float4*>(x)[i];
  v.x *= m; v.y *= m; v.z *= m; v.w *= m;
  reinterpret_cast<float4*>(Xm)[i] = v;
}

// ---------------- final select / masks / compression ----------------------
__global__ __launch_bounds__(256) void select_kernel(
    const float* __restrict__ xf, const float* __restrict__ mf,
    const int* __restrict__ chosen, const float* __restrict__ P2,
    const float* __restrict__ P4, const float* __restrict__ femb,
    float* __restrict__ outs, float* __restrict__ masks, float* __restrict__ comp)
{
  const int row = blockIdx.x;      // 0..1023
  const int tid = threadIdx.x;
  __shared__ float sm_m[32];
  __shared__ int   sm_c[32];
  __shared__ float sm_msum;
  if (tid < 32) { sm_m[tid] = mf[row*32 + tid]; sm_c[tid] = chosen[row*32 + tid]; }
  __syncthreads();
  if (tid == 0) {
    float ms = 0.f, cs = 0.f;
    for (int p = 0; p < 32; ++p) { ms += sm_m[p]; cs += ((float)sm_c[p] / 3.0f) * sm_m[p]; }
    comp[row] = cs / ms;
    sm_msum = ms;
  }
  __syncthreads();
  const float msum = sm_msum;
  const int d0 = tid * 4;
  for (int pos = 0; pos < 32; ++pos) {
    const int c = sm_c[pos];
    float4 o;
    if (c == 0) {
      o = *reinterpret_cast<const float4*>(&xf[((size_t)row*32 + pos) * D_MODEL + d0]);
    } else if (c == 1) {
      float4 e = *reinterpret_cast<const float4*>(&femb[d0]);
      bool valid = (pos < 16) && ((float)pos < msum * 0.5f);
      if (valid) {
        float4 s = *reinterpret_cast<const float4*>(&P2[((size_t)row*16 + pos) * D_MODEL + d0]);
        e.x += s.x; e.y += s.y; e.z += s.z; e.w += s.w;
      }
      o = e;
    } else {
      float4 e = *reinterpret_cast<const float4*>(&femb[D_MODEL + d0]);
      bool valid = (pos < 8) && ((float)pos < msum * 0.25f);
      if (valid) {
        float4 s = *reinterpret_cast<const float4*>(&P4[((size_t)row*8 + pos) * D_MODEL + d0]);
        e.x += s.x; e.y += s.y; e.z += s.z; e.w += s.w;
      }
      o = e;
    }
    *reinterpret_cast<float4*>(&outs[((size_t)row*32 + pos) * D_MODEL + d0]) = o;
    if (tid == 0) {
      float mv;
      if (c == 0)      mv = sm_m[pos];
      else if (c == 1) mv = ((float)pos < msum * 0.5f)  ? 1.f : 0.f;
      else             mv = ((float)pos < msum * 0.25f) ? 1.f : 0.f;
      masks[row*32 + pos] = mv;
    }
  }
}

// ---------------- launch orchestration ------------------------------------
extern "C" void kernel_launch(void* const* d_in, const int* in_sizes, int n_in,
                              void* d_out, int out_size, void* d_ws, size_t ws_size,
                              hipStream_t stream) {
  const float* x       = (const float*)d_in[0];
  const float* mf      = (const float*)d_in[1];
  const float* ln1_w   = (const float*)d_in[2];
  const float* ln1_b   = (const float*)d_in[3];
  const float* wqkv    = (const float*)d_in[4];
  const float* bqkv    = (const float*)d_in[5];
  const float* wo      = (const float*)d_in[6];
  const float* bo      = (const float*)d_in[7];
  const float* ln2_w   = (const float*)d_in[8];
  const float* ln2_b   = (const float*)d_in[9];
  const float* w1      = (const float*)d_in[10];
  const float* b1      = (const float*)d_in[11];
  const float* w2      = (const float*)d_in[12];
  const float* b2      = (const float*)d_in[13];
  const float* rfw     = (const float*)d_in[14];
  const float* rfb     = (const float*)d_in[15];
  const float* pool2_w = (const float*)d_in[16];
  const float* pool2_b = (const float*)d_in[17];
  const float* pool4_w = (const float*)d_in[18];
  const float* pool4_b = (const float*)d_in[19];
  const float* femb    = (const float*)d_in[20];

  // d_out layout: outputs (33.55M floats) | masks (32768) | comp (1024)
  float* out_outputs = (float*)d_out;
  float* out_masks   = out_outputs + (size_t)T_TOK * D_MODEL;
  float* out_comp    = out_masks + T_TOK;

  // X (residual stream) lives in d_out's outputs region (dead before select).
  float* X = out_outputs;

  // d_ws layout (floats): A (33.55M) | B (25.17M) | chosen  => ~235 MB
  float* A = (float*)d_ws;
  float* B = A + (size_t)T_TOK * D_MODEL;
  int* chosen = (int*)(B + (size_t)RCHUNK * NQKV);   // B capacity = 8192*3072
  float* P2 = B;                                     // 1024*16*1024 floats
  float* P4 = B + (size_t)ROWS * 16 * D_MODEL;       // 1024*8*1024 floats
  float* Xm = A;                                     // A free after transformer

  hipMemcpyAsync(X, x, (size_t)T_TOK * D_MODEL * sizeof(float),
                 hipMemcpyDeviceToDevice, stream);

  for (int l = 0; l < LLAYERS; ++l) {
    // LN1 -> A
    ln_kernel<<<T_TOK/4, 256, 0, stream>>>(X, A, ln1_w + l*D_MODEL, ln1_b + l*D_MODEL);
    // qkv + attention, row-chunked (RCHUNK tokens = RCHUNK/32 seqs per chunk)
    for (int rc = 0; rc < T_TOK / RCHUNK; ++rc) {
      const float* Achunk = A + (size_t)rc * RCHUNK * D_MODEL;
      gemm_f32<0><<<dim3(RCHUNK/BM, NQKV/BN), 256, 0, stream>>>(
          Achunk, wqkv + (size_t)l*D_MODEL*NQKV, bqkv + (size_t)l*NQKV, nullptr, B,
          RCHUNK, NQKV, D_MODEL, NQKV);
      attn_kernel<<<(RCHUNK/32)*HEADS, 256, 0, stream>>>(B, mf, A, rc * (RCHUNK/32));
    }
    // o-proj + residual: X = A @ wo[l] + bo[l] + X
    gemm_f32<1><<<dim3(T_TOK/BM, D_MODEL/BN), 256, 0, stream>>>(
        A, wo + (size_t)l*D_MODEL*D_MODEL, bo + (size_t)l*D_MODEL, X, X,
        T_TOK, D_MODEL, D_MODEL, D_MODEL);
    // LN2 -> A
    ln_kernel<<<T_TOK/4, 256, 0, stream>>>(X, A, ln2_w + l*D_MODEL, ln2_b + l*D_MODEL);
    // MLP, DFF-column-chunked: B = gelu(A @ w1[:,c] + b1[c]); X += B @ w2[c,:]
    for (int fc = 0; fc < DFF / FCHUNK; ++fc) {
      gemm_f32<2><<<dim3(T_TOK/BM, FCHUNK/BN), 256, 0, stream>>>(
          A, w1 + (size_t)l*D_MODEL*DFF + fc*FCHUNK, b1 + (size_t)l*DFF + fc*FCHUNK,
          nullptr, B, T_TOK, FCHUNK, D_MODEL, DFF);
      if (fc == 0) {
        gemm_f32<1><<<dim3(T_TOK/BM, D_MODEL/BN), 256, 0, stream>>>(
            B, w2 + (size_t)(l*DFF + fc*FCHUNK)*D_MODEL, b2 + (size_t)l*D_MODEL, X, X,
            T_TOK, D_MODEL, FCHUNK, D_MODEL);
      } else {
        gemm_f32<3><<<dim3(T_TOK/BM, D_MODEL/BN), 256, 0, stream>>>(
            B, w2 + (size_t)(l*DFF + fc*FCHUNK)*D_MODEL, nullptr, X, X,
            T_TOK, D_MODEL, FCHUNK, D_MODEL);
      }
    }
  }

  // router argmax (consumes X before it is overwritten by select)
  router_kernel<<<T_TOK/4, 256, 0, stream>>>(X, rfw, rfb, chosen);

  // masked input for pooling (into A)
  maskmul_kernel<<<T_TOK*D_MODEL/4/256, 256, 0, stream>>>(x, mf, Xm);

  // pool2: (1024*16 x 2048) @ (2048 x 1024) -> P2
  gemm_f32<0><<<dim3(ROWS*16/BM, D_MODEL/BN), 256, 0, stream>>>(
      Xm, pool2_w, pool2_b, nullptr, P2, ROWS*16, D_MODEL, 2*D_MODEL, D_MODEL);
  // pool4: (1024*8 x 4096) @ (4096 x 1024) -> P4
  gemm_f32<0><<<dim3(ROWS*8/BM, D_MODEL/BN), 256, 0, stream>>>(
      Xm, pool4_w, pool4_b, nullptr, P4, ROWS*8, D_MODEL, 4*D_MODEL, D_MODEL);

  // final select + masks + compression (overwrites X region of d_out)
  select_kernel<<<ROWS, 256, 0, stream>>>(x, mf, chosen, P2, P4, femb,
                                          out_outputs, out_masks, out_comp);
}